// Round 8
// baseline (73.639 us; speedup 1.0000x reference)
//
#include <hip/hip_runtime.h>
#include <stdint.h>

#define BATCH   8
#define CDIM    32
#define KLBL    64
#define NPB     200000               // n per batch (6250 * 32)
#define SLABS   6250                 // 32-n slabs per batch
#define CHUNKS  64                   // 64*8 = 512 blocks = 2 per CU exactly
#define REC     (KLBL * CDIM + KLBL) // 2112 floats per partial record

typedef __attribute__((ext_vector_type(8))) short bf16x8;
typedef __attribute__((ext_vector_type(4))) float f32x4;

union ABits { uint32_t u[4]; bf16x8 v; };

__device__ __forceinline__ uint32_t cvtpk_bf16(float lo, float hi) {
  uint32_t r;
  asm volatile("v_cvt_pk_bf16_f32 %0, %1, %2" : "=v"(r) : "v"(lo), "v"(hi));
  return r;
}

// ---------------- Kernel 1: contiguous-stream one-hot MFMA ----------------
// grid = (CHUNKS, BATCH), block = 256 (4 waves = 2 n-subranges x 2 c-halves).
// Per 256-n tile per wave: 17 contiguous 1KB loads (16 pred rows + labels),
// f32->bf16, ds_write to wave-PRIVATE swizzled LDS tile, then 8 slabs of
// one-hot MFMA. No barriers in the loop (nothing shared across waves).
__global__ __launch_bounds__(256) void seg_mfma_kernel(
    const float* __restrict__ pred,    // [B][C][N] f32
    const int*   __restrict__ label,   // [B][N] i32
    float* __restrict__ partial,       // [B][CHUNKS][REC] (fully overwritten)
    float* __restrict__ out) {         // scalar; zeroed here for loss kernel
  __shared__ __align__(16) uint8_t smem[4 * 8448];  // 4 waves x (8KB tile+256B lab)

  const int tid = threadIdx.x;
  const int wv = tid >> 6, ln = tid & 63;
  const int chalf = wv & 1, nsub = wv >> 1;
  const int chunk = blockIdx.x, b = blockIdx.y;

  if (chunk == 0 && b == 0 && tid == 0) out[0] = 0.f;  // loss accumulates later

  uint8_t* tb   = smem + wv * 8448;   // private bf16 tile [16 rows][256 n]
  uint8_t* labb = tb + 8192;          // private packed-u8 labels [256]

  const int s0 = chunk * SLABS / CHUNKS;
  const int s1 = (chunk + 1) * SLABS / CHUNKS;
  const int w0 = s0 + (s1 - s0) * nsub / 2;
  const int w1 = s0 + (s1 - s0) * (nsub + 1) / 2;
  const int W  = w1 - w0;
  const int T  = (W + 7) >> 3;

  const float* pbase = pred + ((size_t)b * CDIM + chalf * 16) * NPB;
  const int*   labp  = label + (size_t)b * NPB;

  const int crow = ln & 15, g = ln >> 4;
  const uint32_t crow_u = (uint32_t)crow;
  const int ln8 = ln * 8;
  const int swz = (ln & 7) << 4;

  ABits ones_;
  ones_.u[0] = ones_.u[1] = ones_.u[2] = ones_.u[3] = 0x3F803F80u;
  const bf16x8 onesv = ones_.v;

  f32x4 acc0 = {0,0,0,0}, acc1 = {0,0,0,0}, acc2 = {0,0,0,0}, acc3 = {0,0,0,0};
  f32x4 cc0  = {0,0,0,0}, cc1  = {0,0,0,0}, cc2  = {0,0,0,0}, cc3  = {0,0,0,0};

  float4 p0, p1, p2, p3, p4, p5, p6, p7, p8, p9, p10, p11, p12, p13, p14, p15;
  int4 lv;

#define LD_ALL(T_)                                                        \
  do {                                                                    \
    const int en_ = min((w0 + (T_) * 8) * 32 + ln * 4, NPB - 4);          \
    p0  = *(const float4*)(pbase + (size_t)0  * NPB + en_);               \
    p1  = *(const float4*)(pbase + (size_t)1  * NPB + en_);               \
    p2  = *(const float4*)(pbase + (size_t)2  * NPB + en_);               \
    p3  = *(const float4*)(pbase + (size_t)3  * NPB + en_);               \
    p4  = *(const float4*)(pbase + (size_t)4  * NPB + en_);               \
    p5  = *(const float4*)(pbase + (size_t)5  * NPB + en_);               \
    p6  = *(const float4*)(pbase + (size_t)6  * NPB + en_);               \
    p7  = *(const float4*)(pbase + (size_t)7  * NPB + en_);               \
    p8  = *(const float4*)(pbase + (size_t)8  * NPB + en_);               \
    p9  = *(const float4*)(pbase + (size_t)9  * NPB + en_);               \
    p10 = *(const float4*)(pbase + (size_t)10 * NPB + en_);               \
    p11 = *(const float4*)(pbase + (size_t)11 * NPB + en_);               \
    p12 = *(const float4*)(pbase + (size_t)12 * NPB + en_);               \
    p13 = *(const float4*)(pbase + (size_t)13 * NPB + en_);               \
    p14 = *(const float4*)(pbase + (size_t)14 * NPB + en_);               \
    p15 = *(const float4*)(pbase + (size_t)15 * NPB + en_);               \
    lv  = *(const int4*)(labp + en_);                                     \
  } while (0)

#define STG_ROW(I_, P_)                                                   \
  do {                                                                    \
    uint2 w_;                                                             \
    w_.x = cvtpk_bf16(P_.x, P_.y);                                        \
    w_.y = cvtpk_bf16(P_.z, P_.w);                                        \
    *(uint2*)(tb + (((I_) * 512 + ln8) ^ (((I_) & 7) << 4))) = w_;        \
  } while (0)

#define KT_STEP(KT_, ACC_, CC_)                                           \
  do {                                                                    \
    ABits a_;                                                             \
    const uint32_t t_ = (uint32_t)((KT_) * 16) + crow_u;                  \
    a_.u[0] = (e0 == t_ ? 0x3F80u : 0u) | (e1 == t_ ? 0x3F800000u : 0u);  \
    a_.u[1] = (e2 == t_ ? 0x3F80u : 0u) | (e3 == t_ ? 0x3F800000u : 0u);  \
    a_.u[2] = (e4 == t_ ? 0x3F80u : 0u) | (e5 == t_ ? 0x3F800000u : 0u);  \
    a_.u[3] = (e6 == t_ ? 0x3F80u : 0u) | (e7 == t_ ? 0x3F800000u : 0u);  \
    ACC_ = __builtin_amdgcn_mfma_f32_16x16x32_bf16(a_.v, bf, ACC_, 0, 0, 0); \
    CC_  = __builtin_amdgcn_mfma_f32_16x16x32_bf16(a_.v, onesv, CC_, 0, 0, 0); \
  } while (0)

  LD_ALL(0);  // prologue: tile 0 in flight

  for (int t = 0; t < T; ++t) {
    // ---- write tile t (regs -> private LDS, swizzled) ----
    const uint32_t pk = (uint32_t)(lv.x & 0xff) | ((uint32_t)(lv.y & 0xff) << 8) |
                        ((uint32_t)(lv.z & 0xff) << 16) | ((uint32_t)(lv.w & 0xff) << 24);
    *(uint32_t*)(labb + ln * 4) = pk;
    STG_ROW(0, p0);   STG_ROW(1, p1);   STG_ROW(2, p2);   STG_ROW(3, p3);
    STG_ROW(4, p4);   STG_ROW(5, p5);   STG_ROW(6, p6);   STG_ROW(7, p7);
    STG_ROW(8, p8);   STG_ROW(9, p9);   STG_ROW(10, p10); STG_ROW(11, p11);
    STG_ROW(12, p12); STG_ROW(13, p13); STG_ROW(14, p14); STG_ROW(15, p15);

    // ---- issue tile t+1 (in flight across the whole consume phase) ----
    if (t + 1 < T) LD_ALL(t + 1);
    __builtin_amdgcn_sched_barrier(0);   // loads must not sink below consume

    // ---- consume tile t: ns slabs of one-hot MFMA ----
    const int ns = min(8, W - t * 8);
    for (int ss = 0; ss < ns; ++ss) {
      const uint2 lw = *(const uint2*)(labb + ss * 32 + g * 8);  // broadcast
      const bf16x8 bf =
          *(const bf16x8*)(tb + ((crow * 512 + ss * 64 + g * 16) ^ swz));
      const uint32_t e0 = lw.x & 0xffu,        e1 = (lw.x >> 8) & 0xffu;
      const uint32_t e2 = (lw.x >> 16) & 0xffu, e3 = lw.x >> 24;
      const uint32_t e4 = lw.y & 0xffu,        e5 = (lw.y >> 8) & 0xffu;
      const uint32_t e6 = (lw.y >> 16) & 0xffu, e7 = lw.y >> 24;
      KT_STEP(0, acc0, cc0);
      KT_STEP(1, acc1, cc1);
      KT_STEP(2, acc2, cc2);
      KT_STEP(3, acc3, cc3);
    }
  }

  // ---- flush: 2 records in LDS (by nsub), c-halves fill disjoint columns --
  __syncthreads();                      // all consumes done; safe to alias smem
  float* sp = (float*)smem;             // s_part[2][REC] aliased onto tiles
#define FLUSH_KT(KT_, ACC_, CC_)                                          \
  do {                                                                    \
    for (int r = 0; r < 4; ++r) {                                         \
      const int k_ = (KT_) * 16 + g * 4 + r;                              \
      sp[nsub * REC + k_ * CDIM + chalf * 16 + crow] = ACC_[r];           \
      if (crow == 0 && chalf == 0) sp[nsub * REC + KLBL * CDIM + k_] = CC_[r]; \
    }                                                                     \
  } while (0)
  FLUSH_KT(0, acc0, cc0);
  FLUSH_KT(1, acc1, cc1);
  FLUSH_KT(2, acc2, cc2);
  FLUSH_KT(3, acc3, cc3);
  __syncthreads();

  float* dst = partial + ((size_t)b * CHUNKS + chunk) * REC;
  for (int i = tid; i < REC; i += 256) dst[i] = sp[i] + sp[REC + i];
}

// ---------------- Kernel 2: reduce partials -> centers -> hinge loss ------
__global__ __launch_bounds__(256) void loss_kernel(
    const float* __restrict__ partial,  // [B][CHUNKS][REC]
    float* __restrict__ out) {          // zeroed by seg block (0,0)
  const int b = blockIdx.x;
  __shared__ float s_rec[REC];
  __shared__ float s_red[256];

  const float* src = partial + (size_t)b * CHUNKS * REC;
  for (int i = threadIdx.x; i < REC; i += 256) {
    float s = 0.f;
    for (int ch = 0; ch < CHUNKS; ++ch) s += src[(size_t)ch * REC + i];
    s_rec[i] = s;
  }
  __syncthreads();
  for (int i = threadIdx.x; i < KLBL * CDIM; i += 256) {
    const float cnt = fmaxf(s_rec[KLBL * CDIM + (i >> 5)], 1.0f);
    s_rec[i] = s_rec[i] / cnt;          // in place; counts region untouched
  }
  __syncthreads();

  float acc = 0.f;
  for (int p = threadIdx.x; p < CDIM * CDIM; p += 256) {
    const int i = p >> 5, j = p & 31;
    float gr = 0.f, ni = 0.f, nj = 0.f;
#pragma unroll
    for (int k = 0; k < KLBL; ++k) {
      const float ci = s_rec[k * CDIM + i];
      const float cj = s_rec[k * CDIM + j];
      gr += ci * cj;
      ni += ci * ci;
      nj += cj * cj;
    }
    float sq = fmaxf(ni + nj - 2.f * gr, 0.f);
    const float dist = (sq > 0.f) ? sqrtf(sq) : 0.f;
    const float h = fmaxf(3.0f - dist, 0.f);   // 2*D_DIST = 3.0
    acc += h * h;
  }

  s_red[threadIdx.x] = acc;
  __syncthreads();
  for (int s = 128; s > 0; s >>= 1) {
    if (threadIdx.x < s) s_red[threadIdx.x] += s_red[threadIdx.x + s];
    __syncthreads();
  }
  if (threadIdx.x == 0)
    atomicAdd(out, s_red[0] / (2.0f * (float)KLBL * ((float)KLBL - 1.0f)));
}

// ---------------- launch ----------------
extern "C" void kernel_launch(void* const* d_in, const int* in_sizes, int n_in,
                              void* d_out, int out_size, void* d_ws, size_t ws_size,
                              hipStream_t stream) {
  const float* pred  = (const float*)d_in[0];
  const int*   label = (const int*)d_in[1];
  float* out = (float*)d_out;

  float* partial = (float*)d_ws;   // 512 * 2112 * 4B = 4.33 MB, fully written

  dim3 grid1(CHUNKS, BATCH);
  seg_mfma_kernel<<<grid1, 256, 0, stream>>>(pred, label, partial, out);
  loss_kernel<<<BATCH, 256, 0, stream>>>(partial, out);
}